// Round 4
// baseline (116.696 us; speedup 1.0000x reference)
//
#include <hip/hip_runtime.h>
#include <cmath>

#define KCLS 10
#define NCELL 3721          // 61*61
#define BIGV  0x0FFFFFFF

// d_out layout (all float32), concatenated in reference return order
#define OUT_PROB 0
#define OUT_LAB  37210
#define OUT_BOX  74420
#define OUT_VALID 223300

// padded pixel-row: raw float index p stored at p + 4*(p/48).
// Read pattern addr = 52*(c+tq) + 4u -> dword-bank 20*(c+tq) mod 32 walks all
// 8 bank-quads with period 8 -> structural-minimum ds_read_b128 (no excess
// conflicts; lanes c and c+8 share a quad = the unavoidable wave64 minimum).
#define XROW_PAD 3328       // 3072 + 4*64

// helper: element n (compile-time after unroll) of a float4[10] block
#define WF(q, n) ( ((n)&3)==0 ? (q)[(n)>>2].x : ((n)&3)==1 ? (q)[(n)>>2].y : \
                   ((n)&3)==2 ? (q)[(n)>>2].z : (q)[(n)>>2].w )

// ---------------- Stage 1a: partial logits ---------------------------------
// Grid 992 = 31 r-pairs x 32 i-pairs; 256 threads = 4 waves (t-quarters),
// lane = patch column c. Main loop touches ONLY LDS: per u-step
//   2 ds_read_b128 (x, rows ra/rb)  +  10 ds_read_b128 (W, wave-uniform
//   address -> hardware broadcast, conflict-free)  +  80 v_fma.
// r-pairing makes each W broadcast feed 2 patches (80 FMA per 10 W reads).
// No barriers, no global/scalar loads in the loop -> compiler-proof.
// Cross-wave (tq) reduce via ds_add_f32; partial layout identical to prior
// round so k1b / k2 are unchanged (verified).
__global__ __launch_bounds__(256, 2) void k1a_partial(
    const float* __restrict__ x, const float* __restrict__ W,
    float* __restrict__ partial)
{
    const int tid  = threadIdx.x;
    const int bid  = blockIdx.x;          // 0..991
    const int i2   = bid / 31;            // 0..31  (i-pair)
    const int g    = bid - i2 * 31;       // 0..30  (r-pair)
    const int ra   = g * 2;               // even patch row 0..60
    const int lane = tid & 63;
    const int tq   = tid >> 6;            // t-quarter 0..3
    const int cc   = (lane < 61) ? lane : 60;   // dup lanes, add-guarded

    __shared__ float xrow[2][2][XROW_PAD];   // [rr][ii][.]  53.2 KiB
    __shared__ float wlds[384 * KCLS];       // W rows for this i2, 15.4 KiB
    __shared__ float red[2][61][KCLS];       // 4.9 KiB

    // zero red (before the single barrier)
    for (int s = tid; s < 2 * 61 * KCLS; s += 256) ((float*)red)[s] = 0.0f;

    // stage W rows d = i2*384 .. +383 (3840 floats, coalesced dwordx4)
    {
        const float* wsrc = W + (size_t)i2 * 3840;
#pragma unroll
        for (int j = 0; j < 4; ++j) {
            const int idx = tid + (j << 8);
            if (idx < 960)
                *(float4*)(wlds + (idx << 2)) = *(const float4*)(wsrc + (idx << 2));
        }
    }
    // stage 4 pixel rows (2 patch-rows x 2 i-rows), padded
#pragma unroll
    for (int rr = 0; rr < 2; ++rr) {
#pragma unroll
        for (int ii = 0; ii < 2; ++ii) {
            int prow = (ra + rr) * 16 + i2 * 2 + ii;
            if (prow > 1023) prow = 1023;        // g=30,rr=1: dup, never written
            const float* gp = x + (size_t)prow * 3072;
#pragma unroll
            for (int j = 0; j < 3; ++j) {
                const int idx = tid + (j << 8);   // 0..767 float4s
                const float4 v = *(const float4*)(gp + (idx << 2));
                const int p = idx << 2;           // p%48 <= 44: same pad group
                float* d = &xrow[rr][ii][p + ((p / 48) << 2)];
                d[0] = v.x; d[1] = v.y; d[2] = v.z; d[3] = v.w;
            }
        }
    }
    __syncthreads();

    float accA[KCLS], accB[KCLS];
#pragma unroll
    for (int k = 0; k < KCLS; ++k) { accA[k] = 0.0f; accB[k] = 0.0f; }

#pragma unroll
    for (int ii = 0; ii < 2; ++ii) {
        const float* wl = wlds + (ii * 192 + tq * 48) * KCLS;  // uniform
        const float* lA = &xrow[0][ii][52 * (cc + tq)];
        const float* lB = &xrow[1][ii][52 * (cc + tq)];
#pragma unroll 2
        for (int u = 0; u < 12; ++u) {
            const float4 xa = *(const float4*)(lA + (u << 2));
            const float4 xb = *(const float4*)(lB + (u << 2));
            const float* wp = wl + 40 * u;        // 16B-aligned, uniform
            float4 wq[10];
#pragma unroll
            for (int q = 0; q < 10; ++q) wq[q] = *(const float4*)(wp + (q << 2));
#pragma unroll
            for (int k = 0; k < KCLS; ++k) {
                accA[k] += xa.x * WF(wq, k);       accB[k] += xb.x * WF(wq, k);
                accA[k] += xa.y * WF(wq, 10 + k);  accB[k] += xb.y * WF(wq, 10 + k);
                accA[k] += xa.z * WF(wq, 20 + k);  accB[k] += xb.z * WF(wq, 20 + k);
                accA[k] += xa.w * WF(wq, 30 + k);  accB[k] += xb.w * WF(wq, 30 + k);
            }
        }
    }

    // cross-wave reduce (ds_add_f32); non-deterministic order perturbs sums
    // only at ~1e-7, decision margins are ~1e-3.
    if (lane < 61) {
#pragma unroll
        for (int k = 0; k < KCLS; ++k) {
            atomicAdd(&red[0][cc][k], accA[k]);
            atomicAdd(&red[1][cc][k], accB[k]);
        }
    }
    __syncthreads();

    // write partials: slot i2, rows ra and ra+1 (layout [i2][r][c][k])
    for (int t = tid; t < 610; t += 256)
        partial[(size_t)i2 * 37210 + (size_t)ra * 610 + t] = ((const float*)red)[t];
    if (ra + 1 <= 60) {
        for (int t = tid; t < 610; t += 256)
            partial[(size_t)i2 * 37210 + (size_t)(ra + 1) * 610 + t]
                = ((const float*)red)[610 + t];
    }
}

// ---------------- Stage 1b: reduce partials + bias + softmax ---------------
__global__ __launch_bounds__(640) void k1b_softmax(
    const float* __restrict__ partial, const float* __restrict__ b,
    float* __restrict__ out)
{
    const int r   = blockIdx.x;           // 0..60
    const int tid = threadIdx.x;
    __shared__ double lgs[61][KCLS];

    if (tid < 610) {
        const int c = tid / 10, k = tid - c * 10;
        double s = (double)b[k];
        const float* p = partial + (size_t)r * 610 + tid;
#pragma unroll 8
        for (int i2 = 0; i2 < 32; ++i2)
            s += (double)p[(size_t)i2 * 37210];
        lgs[c][k] = s;
    }
    __syncthreads();

    if (tid < 61) {
        double l[KCLS];
#pragma unroll
        for (int k = 0; k < KCLS; ++k) l[k] = lgs[tid][k];
        double m = l[0];
#pragma unroll
        for (int k = 1; k < KCLS; ++k) m = fmax(m, l[k]);
        double e[KCLS], ssum = 0.0;
#pragma unroll
        for (int k = 0; k < KCLS; ++k) { e[k] = exp(l[k] - m); ssum += e[k]; }
        const double inv = 1.0 / ssum;
        float* po = out + OUT_PROB + (size_t)(r * 61 + tid) * KCLS;
#pragma unroll
        for (int k = 0; k < KCLS; ++k) po[k] = (float)(e[k] * inv);
    }
}

// ---------------- Stage 2+3 fused: CC (union-find hooking) + boxes ---------
// One block per class. Labels stored as LDS OFFSETS (off = (r+1)*64 + c+1):
// min-off == min-idx (both lexicographic in (r,c)). Root chase + atomicMin
// hooking = path compression -> ~3-6 rounds instead of O(diameter).
__global__ __launch_bounds__(1024) void k2_cc_boxes(float* __restrict__ out)
{
    const int k   = blockIdx.x;
    const int tid = threadIdx.x;

    __shared__ int lab[63 * 64];
    __shared__ int act[NCELL];
    __shared__ int nact, changed;
    __shared__ int rmn[NCELL + 1], rmx[NCELL + 1], cmn[NCELL + 1], cmx[NCELL + 1];

    for (int idx = tid; idx < 63 * 64; idx += 1024) lab[idx] = BIGV;
    for (int s = tid; s <= NCELL; s += 1024) {
        rmn[s] = 0x7fffffff; cmn[s] = 0x7fffffff; rmx[s] = -1; cmx[s] = -1;
    }
    if (tid == 0) nact = 0;
    __syncthreads();

    for (int idx = tid; idx < NCELL; idx += 1024) {
        const float pv = out[OUT_PROB + (size_t)idx * KCLS + k];
        if (pv > 0.7f) {
            const int r = idx / 61, c = idx - r * 61;
            const int off = (r + 1) * 64 + (c + 1);
            lab[off] = off;
            act[atomicAdd(&nact, 1)] = off;
        }
    }
    __syncthreads();
    const int na = nact;

    for (int round = 0; round < 128; ++round) {
        if (tid == 0) changed = 0;
        __syncthreads();
        bool ch = false;
        for (int ii = tid; ii < na; ii += 1024) {
            const int off = act[ii];
            const int v = lab[off];
            int m = v, t;
            t = lab[off - 1];  if (t < m) m = t;
            t = lab[off + 1];  if (t < m) m = t;
            t = lab[off - 64]; if (t < m) m = t;
            t = lab[off + 64]; if (t < m) m = t;
            if (m < v) {
                int p = lab[m];                       // chase to current root
                while (p < m) { m = p; p = lab[m]; }  // strictly decreasing
                atomicMin(&lab[off], m);              // compress self
                atomicMin(&lab[v],   m);              // hook old root (union)
                ch = true;
            }
        }
        if (ch) changed = 1;       // benign race
        __syncthreads();
        if (changed == 0) break;   // no writes between the barriers -> uniform
        __syncthreads();           // protect next round's reset
    }

    // write labels (convert off -> idx+1)
    for (int idx = tid; idx < NCELL; idx += 1024) {
        const int r = idx / 61, c = idx - r * 61;
        const int v = lab[(r + 1) * 64 + (c + 1)];
        const int lv = (v < BIGV) ? ((v >> 6) * 61 - 61 + (v & 63)) : 0;
        out[OUT_LAB + (size_t)idx * KCLS + k] = (float)lv;
    }

    // boxes: segment min/max over active cells only
    for (int ii = tid; ii < na; ii += 1024) {
        const int off = act[ii];
        const int v = lab[off];
        const int lb = (v >> 6) * 61 - 61 + (v & 63);
        const int r = (off >> 6) - 1, c = (off & 63) - 1;
        atomicMin(&rmn[lb], r); atomicMax(&rmx[lb], r);
        atomicMin(&cmn[lb], c); atomicMax(&cmx[lb], c);
    }
    __syncthreads();

    for (int s = tid; s <= NCELL; s += 1024) {
        const bool val = (s > 0) && (rmx[s] >= 0);
        float* bo = out + OUT_BOX + (size_t)(k * (NCELL + 1) + s) * 4;
        if (val) {
            bo[0] = (float)(rmn[s] - 1);
            bo[1] = (float)(cmn[s] - 1);
            bo[2] = (float)(rmx[s] + 1);
            bo[3] = (float)(cmx[s] + 1);
        } else {
            bo[0] = 0.0f; bo[1] = 0.0f; bo[2] = 0.0f; bo[3] = 0.0f;
        }
        out[OUT_VALID + (size_t)k * (NCELL + 1) + s] = val ? 1.0f : 0.0f;
    }
}

extern "C" void kernel_launch(void* const* d_in, const int* in_sizes, int n_in,
                              void* d_out, int out_size, void* d_ws, size_t ws_size,
                              hipStream_t stream) {
    const float* x = (const float*)d_in[0];   // (1,1024,1024,3) f32
    const float* W = (const float*)d_in[1];   // (12288,10) f32
    const float* b = (const float*)d_in[2];   // (10,) f32
    float* out     = (float*)d_out;
    float* partial = (float*)d_ws;            // 32*61*61*10 f32 = 4.77 MB

    k1a_partial<<<dim3(992), dim3(256), 0, stream>>>(x, W, partial);
    k1b_softmax<<<dim3(61),  dim3(640), 0, stream>>>(partial, b, out);
    k2_cc_boxes<<<dim3(KCLS), dim3(1024), 0, stream>>>(out);
}